// Round 12
// baseline (360.223 us; speedup 1.0000x reference)
//
#include <hip/hip_runtime.h>
#include <math.h>

// Problem constants
constexpr int T_ = 1024, S_ = 1024, B_ = 4, E_ = 1024, H_ = 16, D_ = 64;
constexpr float SCALE_ = 0.125f;                  // D^-0.5
constexpr size_t NH_ = (size_t)B_ * H_ * T_ * D_; // 4,194,304 elems
constexpr size_t EE_ = (size_t)E_ * E_;           // 1,048,576 elems

typedef _Float16 h8 __attribute__((ext_vector_type(8)));
typedef _Float16 h4 __attribute__((ext_vector_type(4)));
typedef float f4 __attribute__((ext_vector_type(4)));

__device__ inline f4 mfma16(h8 a, h8 b, f4 c) {
    return __builtin_amdgcn_mfma_f32_16x16x32_f16(a, b, c, 0, 0, 0);
}
// K=16 variant: A-frag = lane(lr,lg) holds A[row=lr][k=lg*4..+4]
__device__ inline f4 mfma16x16(h4 a, h4 b, f4 c) {
    return __builtin_amdgcn_mfma_f32_16x16x16f16(a, b, c, 0, 0, 0);
}

// async global->LDS, 16B per lane; lds dest = wave-uniform base + lane*16
__device__ inline void gload_lds16(const void* g, void* l) {
    __builtin_amdgcn_global_load_lds(
        (const __attribute__((address_space(1))) void*)g,
        (__attribute__((address_space(3))) void*)l, 16, 0, 0);
}

// ---------------------------------------------------------------------------
// Fused f32 -> f16 converter for all 7 tensors (outputs contiguous in ws).
// ---------------------------------------------------------------------------
__global__ __launch_bounds__(256) void cvt_all(
    const float* __restrict__ q, const float* __restrict__ k,
    const float* __restrict__ v, const float* __restrict__ wq,
    const float* __restrict__ wk, const float* __restrict__ wv,
    const float* __restrict__ wp, _Float16* __restrict__ dst)
{
    const int i8 = blockIdx.x * 256 + threadIdx.x;   // 0 .. 2097151
    constexpr int BIG = (int)(NH_ / 8);              // 524288
    constexpr int WSZ = (int)(EE_ / 8);              // 131072
    const float* src;
    int loc;
    if (i8 < 3 * BIG) {
        int t = i8 / BIG; loc = i8 - t * BIG;
        src = t == 0 ? q : (t == 1 ? k : v);
    } else {
        int r = i8 - 3 * BIG;
        int t = r / WSZ; loc = r - t * WSZ;
        src = t == 0 ? wq : (t == 1 ? wk : (t == 2 ? wv : wp));
    }
    const float* p = src + (size_t)loc * 8;
    float4 a = *(const float4*)p;
    float4 b = *(const float4*)(p + 4);
    h8 o;
    o[0] = (_Float16)a.x; o[1] = (_Float16)a.y;
    o[2] = (_Float16)a.z; o[3] = (_Float16)a.w;
    o[4] = (_Float16)b.x; o[5] = (_Float16)b.y;
    o[6] = (_Float16)b.z; o[7] = (_Float16)b.w;
    *(h8*)&dst[(size_t)i8 * 8] = o;
}

// ---------------------------------------------------------------------------
// GEMM core: 64x128 tile, BK=64, 512 thr = 8 waves (2x4), wave tile 32x32.
// ---------------------------------------------------------------------------
template <typename EPI>
__device__ inline void gemm_core(
    const _Float16* __restrict__ A, const _Float16* __restrict__ W,
    int m0, int n0, EPI epi)
{
    __shared__ _Float16 As[64][64];    //  8 KB linear
    __shared__ _Float16 Bs[128][64];   // 16 KB linear

    const int tid = threadIdx.x;
    const int w = tid >> 6, l = tid & 63, lr = l & 15, lg = l >> 4;
    const int wr = w >> 2, wc = w & 3;

    const int srow = (w << 3) + (l >> 3);       // 0..63 staged row
    const int sg   = (l & 7) ^ (srow & 7);      // swizzled source chunk
    char* AsB = (char*)As;
    char* BsB = (char*)Bs;
    char* ldsA  = AsB + w * 1024;
    char* ldsB0 = BsB + w * 1024;
    char* ldsB1 = BsB + 8192 + w * 1024;

    f4 acc[2][2];
#pragma unroll
    for (int mi = 0; mi < 2; ++mi)
#pragma unroll
        for (int ni = 0; ni < 2; ++ni) acc[mi][ni] = (f4){0.f, 0.f, 0.f, 0.f};

    for (int k0 = 0; k0 < 1024; k0 += 64) {
        gload_lds16(&A[(size_t)(m0 + srow) * 1024 + k0 + sg * 8], ldsA);
        gload_lds16(&W[(size_t)(n0 + srow) * 1024 + k0 + sg * 8], ldsB0);
        gload_lds16(&W[(size_t)(n0 + 64 + srow) * 1024 + k0 + sg * 8], ldsB1);
        __syncthreads();
#pragma unroll
        for (int kk = 0; kk < 2; ++kk) {
            h8 af[2], bf[2];
#pragma unroll
            for (int mi = 0; mi < 2; ++mi) {
                int r = wr * 32 + mi * 16 + lr, kc = kk * 4 + lg;
                af[mi] = *(const h8*)(AsB + r * 128 + ((kc ^ (r & 7)) << 4));
            }
#pragma unroll
            for (int ni = 0; ni < 2; ++ni) {
                int r = wc * 32 + ni * 16 + lr, kc = kk * 4 + lg;
                bf[ni] = *(const h8*)(BsB + r * 128 + ((kc ^ (r & 7)) << 4));
            }
#pragma unroll
            for (int mi = 0; mi < 2; ++mi)
#pragma unroll
                for (int ni = 0; ni < 2; ++ni)
                    acc[mi][ni] = mfma16(af[mi], bf[ni], acc[mi][ni]);
        }
        __syncthreads();
    }

#pragma unroll
    for (int mi = 0; mi < 2; ++mi)
#pragma unroll
        for (int ni = 0; ni < 2; ++ni)
#pragma unroll
            for (int r = 0; r < 4; ++r) {
                int row = m0 + wr * 32 + mi * 16 + lg * 4 + r;
                int col = n0 + wc * 32 + ni * 16 + lr;
                epi(row, col, acc[mi][ni][r]);
            }
}

// ---------------------------------------------------------------------------
// Merged Q/K/V projection: blockIdx.z selects tensor.
// ---------------------------------------------------------------------------
__global__ __launch_bounds__(512) void qkv_gemm(
    const _Float16* __restrict__ q16, const _Float16* __restrict__ k16,
    const _Float16* __restrict__ v16, const _Float16* __restrict__ Wq16,
    const _Float16* __restrict__ Wk16, const _Float16* __restrict__ Wv16,
    _Float16* __restrict__ qh, _Float16* __restrict__ kh,
    _Float16* __restrict__ vhT)
{
    const int z = blockIdx.z;
    const _Float16* A = z == 0 ? q16 : (z == 1 ? k16 : v16);
    const _Float16* W = z == 0 ? Wq16 : (z == 1 ? Wk16 : Wv16);
    _Float16* C = z == 0 ? qh : (z == 1 ? kh : vhT);
    const float scale = (z == 0) ? SCALE_ : 1.0f;
    const int m0 = blockIdx.x * 64, n0 = blockIdx.y * 128;

    if (z < 2) {
        gemm_core(A, W, m0, n0, [&](int row, int col, float vv) {
            int t = row >> 2, b = row & 3, h = col >> 6, d = col & 63;
            C[(((size_t)b * H_ + h) * T_ + t) * D_ + d] = (_Float16)(vv * scale);
        });
    } else {
        gemm_core(A, W, m0, n0, [&](int row, int col, float vv) {
            int s = row >> 2, b = row & 3, h = col >> 6, d = col & 63;
            C[(((size_t)b * H_ + h) * D_ + d) * S_ + s] = (_Float16)vv;
        });
    }
}

// ---------------------------------------------------------------------------
// Output projection: out = oh @ Wp^T + bp  (f32 out)
// ---------------------------------------------------------------------------
__global__ __launch_bounds__(512) void out_gemm(
    const _Float16* __restrict__ oh, const _Float16* __restrict__ Wp16,
    const float* __restrict__ bp, float* __restrict__ out)
{
    const int m0 = blockIdx.x * 64, n0 = blockIdx.y * 128;
    gemm_core(oh, Wp16, m0, n0, [&](int row, int col, float vv) {
        out[(size_t)row * E_ + col] = vv + bp[col];
    });
}

// ---------------------------------------------------------------------------
// Fused attention v3: single-pass, ONE barrier.
// Per (bh, 16-row t-tile), 512 thr = 8 waves; wave owns a 128-s stripe.
//   loop over 8 subs (16 s each):
//     K h8 loads -> QK^T via mfma 16x16x32 (swapped: lane(lr,lg) reg r holds
//       S[t0+lr][s0+lg*4+r]);
//     bias f4 + mask int4 loads (same layout); p = mask?0:exp(S+bias) in REGS
//     PV partial via mfma 16x16x16: A-frag IS p (row=lr=t? no: row=lr matches
//       A[row][k]=P[t0+lr][s0+lg*4+j]), B = vhT h4 -> opv[db] accumulates
//       O_w[t=lg*4+r][d=db*16+lr] over this wave's s-stripe.
//   rowsum shfl-reduce -> wsum; O partials -> LDS;  __syncthreads (ONLY one)
//   epilogue: inv from wsum; attn = p*inv streamed (plain stores, L2-merged);
//             O = sum_w O_w * inv -> oh.
// Grid: 1D 4096, XCD-swizzled.
// ---------------------------------------------------------------------------
__global__ __launch_bounds__(512, 4) void fused_attn(
    const _Float16* __restrict__ qh, const _Float16* __restrict__ kh,
    const _Float16* __restrict__ vhT, const float* __restrict__ bias,
    const int* __restrict__ mask, float* __restrict__ attn,
    _Float16* __restrict__ oh)
{
    __shared__ float Ow[8][16][66];      // 33.8 KB, stride 66 (2-way free)
    __shared__ float wsum[8][16];

    const int bid = blockIdx.x;
    const int vid = (bid & 7) * 512 + (bid >> 3);   // 4096 % 8 == 0, bijective
    const int bh = vid >> 6;              // 0..63
    const int t0 = (vid & 63) * 16;       // 0..1008
    const int b = bh >> 4, h = bh & 15;
    const int tid = threadIdx.x;
    const int w = tid >> 6, l = tid & 63, lr = l & 15, lg = l >> 4;
    const int wbase = w * 128;            // this wave's s-stripe

    const float* brow = bias + ((size_t)bh * T_ + t0 + lr) * S_ + wbase + lg * 4;
    const int*   mrow = mask + (size_t)b * S_ + wbase + lg * 4;
    const _Float16* kbase = kh + (size_t)bh * S_ * D_;
    const _Float16* vbase = vhT + (size_t)bh * D_ * S_;

    const _Float16* qbase = qh + ((size_t)bh * T_ + t0) * D_;
    h8 qf0 = *(const h8*)&qbase[(size_t)lr * D_ + lg * 8];
    h8 qf1 = *(const h8*)&qbase[(size_t)lr * D_ + 32 + lg * 8];

    f4 p[8];
    f4 opv[4];
#pragma unroll
    for (int db = 0; db < 4; ++db) opv[db] = (f4){0.f, 0.f, 0.f, 0.f};
    float rs = 0.f;

#pragma unroll
    for (int sub = 0; sub < 8; ++sub) {
        const int s0 = wbase + sub * 16;
        h8 kf0 = *(const h8*)&kbase[(size_t)(s0 + lr) * D_ + lg * 8];
        h8 kf1 = *(const h8*)&kbase[(size_t)(s0 + lr) * D_ + 32 + lg * 8];
        f4 bv = *(const f4*)&brow[sub * 16];
        int4 mv = *(const int4*)&mrow[sub * 16];

        f4 c = (f4){0.f, 0.f, 0.f, 0.f};
        c = mfma16(kf0, qf0, c);
        c = mfma16(kf1, qf1, c);

        f4 pj;
        pj[0] = mv.x ? 0.f : __expf(c[0] + bv[0]);
        pj[1] = mv.y ? 0.f : __expf(c[1] + bv[1]);
        pj[2] = mv.z ? 0.f : __expf(c[2] + bv[2]);
        pj[3] = mv.w ? 0.f : __expf(c[3] + bv[3]);
        rs += (pj[0] + pj[1]) + (pj[2] + pj[3]);
        p[sub] = pj;

        h4 pa;
        pa[0] = (_Float16)pj[0]; pa[1] = (_Float16)pj[1];
        pa[2] = (_Float16)pj[2]; pa[3] = (_Float16)pj[3];
#pragma unroll
        for (int db = 0; db < 4; ++db) {
            h4 vf = *(const h4*)&vbase[(size_t)(db * 16 + lr) * S_ + s0 + lg * 4];
            opv[db] = mfma16x16(pa, vf, opv[db]);
        }
    }

    // rowsum for t = t0+lr: sum lg groups (lanes lr, lr+16, lr+32, lr+48)
    rs += __shfl_xor(rs, 16); rs += __shfl_xor(rs, 32);
    if (l < 16) wsum[w][lr] = rs;

    // O partials -> LDS: Ow[w][t=lg*4+r][d=db*16+lr]
#pragma unroll
    for (int db = 0; db < 4; ++db)
#pragma unroll
        for (int r = 0; r < 4; ++r)
            Ow[w][lg * 4 + r][db * 16 + lr] = opv[db][r];

    __syncthreads();                      // the only barrier

    // ---- epilogue A: attn stream from regs (row t0+lr) ----
    {
        float s8 = 0.f;
#pragma unroll
        for (int ww = 0; ww < 8; ++ww) s8 += wsum[ww][lr];   // broadcast
        const float inv = 1.0f / s8;
        float* arow = attn + ((size_t)bh * T_ + t0 + lr) * S_ + wbase + lg * 4;
#pragma unroll
        for (int sub = 0; sub < 8; ++sub) {
            f4 o = {p[sub][0] * inv, p[sub][1] * inv,
                    p[sub][2] * inv, p[sub][3] * inv};
            *(f4*)&arow[sub * 16] = o;    // plain store: L2 merges 64B halves
        }
    }

    // ---- epilogue B: O reduce over 8 waves + oh write ----
#pragma unroll
    for (int rep = 0; rep < 2; ++rep) {
        int idx = tid + rep * 512;        // 0..1023
        int t = idx >> 6, d = idx & 63;
        float o = 0.f, s = 0.f;
#pragma unroll
        for (int ww = 0; ww < 8; ++ww) {
            o += Ow[ww][t][d];
            s += wsum[ww][t];
        }
        o /= s;
        oh[((size_t)(t0 + t) * B_ + b) * E_ + h * 64 + d] = (_Float16)o;
    }
}

// ---------------------------------------------------------------------------
extern "C" void kernel_launch(void* const* d_in, const int* in_sizes, int n_in,
                              void* d_out, int out_size, void* d_ws, size_t ws_size,
                              hipStream_t stream)
{
    const float* q    = (const float*)d_in[0];
    const float* k    = (const float*)d_in[1];
    const float* v    = (const float*)d_in[2];
    const float* Wq   = (const float*)d_in[3];
    const float* Wk   = (const float*)d_in[4];
    const float* Wv   = (const float*)d_in[5];
    const float* Wp   = (const float*)d_in[6];
    const float* bp   = (const float*)d_in[7];
    const float* bias = (const float*)d_in[8];
    const int*   mask = (const int*)d_in[9];

    float* out  = (float*)d_out;               // (T,B,E) f32
    float* attn = out + (size_t)T_ * B_ * E_;  // (B,H,T,S) f32

    _Float16* qh   = (_Float16*)d_ws;          // (B,H,T,D)
    _Float16* kh   = qh + NH_;                 // (B,H,S,D)
    _Float16* vhT  = kh + NH_;                 // (B,H,D,S)
    _Float16* oh   = vhT + NH_;                // (T,B,E)
    _Float16* q16  = oh + NH_;                 // contiguous cvt_all dst
    _Float16* k16  = q16 + NH_;
    _Float16* v16  = k16 + NH_;
    _Float16* Wq16 = v16 + NH_;
    _Float16* Wk16 = Wq16 + EE_;
    _Float16* Wv16 = Wk16 + EE_;
    _Float16* Wp16 = Wv16 + EE_;

    dim3 blk(512);

    cvt_all<<<dim3(8192), dim3(256), 0, stream>>>(q, k, v, Wq, Wk, Wv, Wp, q16);

    qkv_gemm<<<dim3(64, 8, 3), blk, 0, stream>>>(
        q16, k16, v16, Wq16, Wk16, Wv16, qh, kh, vhT);

    fused_attn<<<dim3(4096), blk, 0, stream>>>(qh, kh, vhT, bias, mask, attn, oh);

    out_gemm<<<dim3(64, 8), blk, 0, stream>>>(oh, Wp16, bp, out);
}

// Round 13
// 290.737 us; speedup vs baseline: 1.2390x; 1.2390x over previous
//
#include <hip/hip_runtime.h>
#include <math.h>

// Problem constants
constexpr int T_ = 1024, S_ = 1024, B_ = 4, E_ = 1024, H_ = 16, D_ = 64;
constexpr float SCALE_ = 0.125f;                  // D^-0.5
constexpr size_t NH_ = (size_t)B_ * H_ * T_ * D_; // 4,194,304 elems
constexpr size_t EE_ = (size_t)E_ * E_;           // 1,048,576 elems

typedef _Float16 h8 __attribute__((ext_vector_type(8)));
typedef _Float16 h4 __attribute__((ext_vector_type(4)));
typedef float f4 __attribute__((ext_vector_type(4)));

__device__ inline f4 mfma16(h8 a, h8 b, f4 c) {
    return __builtin_amdgcn_mfma_f32_16x16x32_f16(a, b, c, 0, 0, 0);
}

// async global->LDS, 16B per lane; lds dest = wave-uniform base + lane*16
__device__ inline void gload_lds16(const void* g, void* l) {
    __builtin_amdgcn_global_load_lds(
        (const __attribute__((address_space(1))) void*)g,
        (__attribute__((address_space(3))) void*)l, 16, 0, 0);
}

// ---------------------------------------------------------------------------
// Fused f32 -> f16 converter for all 7 tensors (outputs contiguous in ws).
// ---------------------------------------------------------------------------
__global__ __launch_bounds__(256) void cvt_all(
    const float* __restrict__ q, const float* __restrict__ k,
    const float* __restrict__ v, const float* __restrict__ wq,
    const float* __restrict__ wk, const float* __restrict__ wv,
    const float* __restrict__ wp, _Float16* __restrict__ dst)
{
    const int i8 = blockIdx.x * 256 + threadIdx.x;   // 0 .. 2097151
    constexpr int BIG = (int)(NH_ / 8);              // 524288
    constexpr int WSZ = (int)(EE_ / 8);              // 131072
    const float* src;
    int loc;
    if (i8 < 3 * BIG) {
        int t = i8 / BIG; loc = i8 - t * BIG;
        src = t == 0 ? q : (t == 1 ? k : v);
    } else {
        int r = i8 - 3 * BIG;
        int t = r / WSZ; loc = r - t * WSZ;
        src = t == 0 ? wq : (t == 1 ? wk : (t == 2 ? wv : wp));
    }
    const float* p = src + (size_t)loc * 8;
    float4 a = *(const float4*)p;
    float4 b = *(const float4*)(p + 4);
    h8 o;
    o[0] = (_Float16)a.x; o[1] = (_Float16)a.y;
    o[2] = (_Float16)a.z; o[3] = (_Float16)a.w;
    o[4] = (_Float16)b.x; o[5] = (_Float16)b.y;
    o[6] = (_Float16)b.z; o[7] = (_Float16)b.w;
    *(h8*)&dst[(size_t)i8 * 8] = o;
}

// ---------------------------------------------------------------------------
// GEMM core: 64x128 tile, BK=64, 512 thr = 8 waves (2x4), wave tile 32x32.
// ---------------------------------------------------------------------------
template <typename EPI>
__device__ inline void gemm_core(
    const _Float16* __restrict__ A, const _Float16* __restrict__ W,
    int m0, int n0, EPI epi)
{
    __shared__ _Float16 As[64][64];    //  8 KB linear
    __shared__ _Float16 Bs[128][64];   // 16 KB linear

    const int tid = threadIdx.x;
    const int w = tid >> 6, l = tid & 63, lr = l & 15, lg = l >> 4;
    const int wr = w >> 2, wc = w & 3;

    const int srow = (w << 3) + (l >> 3);       // 0..63 staged row
    const int sg   = (l & 7) ^ (srow & 7);      // swizzled source chunk
    char* AsB = (char*)As;
    char* BsB = (char*)Bs;
    char* ldsA  = AsB + w * 1024;
    char* ldsB0 = BsB + w * 1024;
    char* ldsB1 = BsB + 8192 + w * 1024;

    f4 acc[2][2];
#pragma unroll
    for (int mi = 0; mi < 2; ++mi)
#pragma unroll
        for (int ni = 0; ni < 2; ++ni) acc[mi][ni] = (f4){0.f, 0.f, 0.f, 0.f};

    for (int k0 = 0; k0 < 1024; k0 += 64) {
        gload_lds16(&A[(size_t)(m0 + srow) * 1024 + k0 + sg * 8], ldsA);
        gload_lds16(&W[(size_t)(n0 + srow) * 1024 + k0 + sg * 8], ldsB0);
        gload_lds16(&W[(size_t)(n0 + 64 + srow) * 1024 + k0 + sg * 8], ldsB1);
        __syncthreads();
#pragma unroll
        for (int kk = 0; kk < 2; ++kk) {
            h8 af[2], bf[2];
#pragma unroll
            for (int mi = 0; mi < 2; ++mi) {
                int r = wr * 32 + mi * 16 + lr, kc = kk * 4 + lg;
                af[mi] = *(const h8*)(AsB + r * 128 + ((kc ^ (r & 7)) << 4));
            }
#pragma unroll
            for (int ni = 0; ni < 2; ++ni) {
                int r = wc * 32 + ni * 16 + lr, kc = kk * 4 + lg;
                bf[ni] = *(const h8*)(BsB + r * 128 + ((kc ^ (r & 7)) << 4));
            }
#pragma unroll
            for (int mi = 0; mi < 2; ++mi)
#pragma unroll
                for (int ni = 0; ni < 2; ++ni)
                    acc[mi][ni] = mfma16(af[mi], bf[ni], acc[mi][ni]);
        }
        __syncthreads();
    }

#pragma unroll
    for (int mi = 0; mi < 2; ++mi)
#pragma unroll
        for (int ni = 0; ni < 2; ++ni)
#pragma unroll
            for (int r = 0; r < 4; ++r) {
                int row = m0 + wr * 32 + mi * 16 + lg * 4 + r;
                int col = n0 + wc * 32 + ni * 16 + lr;
                epi(row, col, acc[mi][ni][r]);
            }
}

// ---------------------------------------------------------------------------
// Merged Q/K/V projection: blockIdx.z selects tensor.
// ---------------------------------------------------------------------------
__global__ __launch_bounds__(512) void qkv_gemm(
    const _Float16* __restrict__ q16, const _Float16* __restrict__ k16,
    const _Float16* __restrict__ v16, const _Float16* __restrict__ Wq16,
    const _Float16* __restrict__ Wk16, const _Float16* __restrict__ Wv16,
    _Float16* __restrict__ qh, _Float16* __restrict__ kh,
    _Float16* __restrict__ vhT)
{
    const int z = blockIdx.z;
    const _Float16* A = z == 0 ? q16 : (z == 1 ? k16 : v16);
    const _Float16* W = z == 0 ? Wq16 : (z == 1 ? Wk16 : Wv16);
    _Float16* C = z == 0 ? qh : (z == 1 ? kh : vhT);
    const float scale = (z == 0) ? SCALE_ : 1.0f;
    const int m0 = blockIdx.x * 64, n0 = blockIdx.y * 128;

    if (z < 2) {
        gemm_core(A, W, m0, n0, [&](int row, int col, float vv) {
            int t = row >> 2, b = row & 3, h = col >> 6, d = col & 63;
            C[(((size_t)b * H_ + h) * T_ + t) * D_ + d] = (_Float16)(vv * scale);
        });
    } else {
        gemm_core(A, W, m0, n0, [&](int row, int col, float vv) {
            int s = row >> 2, b = row & 3, h = col >> 6, d = col & 63;
            C[(((size_t)b * H_ + h) * D_ + d) * S_ + s] = (_Float16)vv;
        });
    }
}

// ---------------------------------------------------------------------------
// Output projection: out = oh @ Wp^T + bp  (f32 out)
// ---------------------------------------------------------------------------
__global__ __launch_bounds__(512) void out_gemm(
    const _Float16* __restrict__ oh, const _Float16* __restrict__ Wp16,
    const float* __restrict__ bp, float* __restrict__ out)
{
    const int m0 = blockIdx.x * 64, n0 = blockIdx.y * 128;
    gemm_core(oh, Wp16, m0, n0, [&](int row, int col, float vv) {
        out[(size_t)row * E_ + col] = vv + bp[col];
    });
}

// ---------------------------------------------------------------------------
// score_attn: per (bh, 16-row t-tile), 512 thr = 8 waves, wave = 128-s stripe.
// Bias streamed via global_load_lds DMA (8x 1KB per wave, wave-private LDS,
// no barrier needed for it) -> high outstanding-bytes, VGPR-free.
//   entry: 8 bias DMAs + Q frags + then vmcnt(0) drain (once per block).
//   loop : K h8 (L2) -> QK^T swapped MFMA; bias f4 from LDS; mask int4 (L2);
//          p[sub] = mask?0:exp(c+bias) in regs; rowsum.
//   one __syncthreads (cross-wave rowsum) -> normalize -> attn from regs
//   (plain f4 stores, L2 merges 64B halves -- verified WRITE=270MB in R12).
// LDS: bias 64KB + wsum -> 2 blocks/CU.
// ---------------------------------------------------------------------------
__global__ __launch_bounds__(512, 4) void score_attn(
    const _Float16* __restrict__ qh, const _Float16* __restrict__ kh,
    const float* __restrict__ bias, const int* __restrict__ mask,
    float* __restrict__ attn)
{
    __shared__ float biasLds[8][8][256];   // [wave][sub][lane*4] = 64 KB
    __shared__ float wsum[8][16];

    const int bid = blockIdx.x;
    const int vid = (bid & 7) * 512 + (bid >> 3);   // 4096 % 8 == 0, bijective
    const int bh = vid >> 6;              // 0..63
    const int t0 = (vid & 63) * 16;       // 0..1008
    const int b = bh >> 4;
    const int tid = threadIdx.x;
    const int w = tid >> 6, l = tid & 63, lr = l & 15, lg = l >> 4;
    const int wbase = w * 128;            // this wave's s-stripe

    // ---- bias DMA: lane l stages row t0+(l>>2), cols wbase+sub*16+(l&3)*4 --
    const float* bsrc = bias + ((size_t)bh * T_ + t0 + (l >> 2)) * S_
                             + wbase + (l & 3) * 4;
#pragma unroll
    for (int sub = 0; sub < 8; ++sub)
        gload_lds16(bsrc + sub * 16, &biasLds[w][sub][0]);

    // Q fragments (issued during DMA drain window)
    const _Float16* qbase = qh + ((size_t)bh * T_ + t0) * D_;
    h8 qf0 = *(const h8*)&qbase[(size_t)lr * D_ + lg * 8];
    h8 qf1 = *(const h8*)&qbase[(size_t)lr * D_ + 32 + lg * 8];

    __builtin_amdgcn_sched_barrier(0);
    asm volatile("s_waitcnt vmcnt(0)" ::: "memory");   // DMA + Q arrived
    __builtin_amdgcn_sched_barrier(0);

    const _Float16* kbase = kh + (size_t)bh * S_ * D_;
    const int* mrow = mask + (size_t)b * S_ + wbase + lg * 4;
    const float* bw = &biasLds[w][0][(lr * 4 + lg) * 4];   // consumer slot

    f4 p[8];
    float rs = 0.f;
#pragma unroll
    for (int sub = 0; sub < 8; ++sub) {
        const int s0 = wbase + sub * 16;
        h8 kf0 = *(const h8*)&kbase[(size_t)(s0 + lr) * D_ + lg * 8];
        h8 kf1 = *(const h8*)&kbase[(size_t)(s0 + lr) * D_ + 32 + lg * 8];
        f4 bv = *(const f4*)(bw + sub * 256);
        int4 mv = *(const int4*)&mrow[sub * 16];

        f4 c = (f4){0.f, 0.f, 0.f, 0.f};
        c = mfma16(kf0, qf0, c);
        c = mfma16(kf1, qf1, c);

        f4 pj;
        pj[0] = mv.x ? 0.f : __expf(c[0] + bv[0]);
        pj[1] = mv.y ? 0.f : __expf(c[1] + bv[1]);
        pj[2] = mv.z ? 0.f : __expf(c[2] + bv[2]);
        pj[3] = mv.w ? 0.f : __expf(c[3] + bv[3]);
        rs += (pj[0] + pj[1]) + (pj[2] + pj[3]);
        p[sub] = pj;
    }

    // rowsum for t = t0+lr: sum lg groups, then cross-wave via LDS
    rs += __shfl_xor(rs, 16); rs += __shfl_xor(rs, 32);
    if (l < 16) wsum[w][lr] = rs;
    __syncthreads();                      // the only barrier

    float s8 = 0.f;
#pragma unroll
    for (int ww = 0; ww < 8; ++ww) s8 += wsum[ww][lr];   // broadcast reads
    const float inv = 1.0f / s8;

    float* arow = attn + ((size_t)bh * T_ + t0 + lr) * S_ + wbase + lg * 4;
#pragma unroll
    for (int sub = 0; sub < 8; ++sub) {
        f4 o = {p[sub][0] * inv, p[sub][1] * inv,
                p[sub][2] * inv, p[sub][3] * inv};
        *(f4*)&arow[sub * 16] = o;        // plain store: L2 merges
    }
}

// ---------------------------------------------------------------------------
// pv_heads: O = attn_norm @ V^T per bh. Block = 128 t x 64 d, BK=64, 512 thr.
// A (attn f32, L2/L3-warm) staged with inline cvt + swizzled ds_write;
// B (vhT f16) via gload_lds with source-swizzle. Same read-swizzle as
// gemm_core. Waves: wr=w>>2 (m 64 each), wc=w&3 (n 16 each), acc 4x16.
// ---------------------------------------------------------------------------
__global__ __launch_bounds__(512) void pv_heads(
    const float* __restrict__ attn, const _Float16* __restrict__ vhT,
    _Float16* __restrict__ oh)
{
    __shared__ _Float16 As[128][64];   // 16 KB
    __shared__ _Float16 Bs[64][64];    //  8 KB

    const int bh = blockIdx.y;
    const int b = bh >> 4, h = bh & 15;
    const int m0 = blockIdx.x * 128;
    const int tid = threadIdx.x;
    const int w = tid >> 6, l = tid & 63, lr = l & 15, lg = l >> 4;
    const int wr = w >> 2, wc = w & 3;

    const float* abase = attn + ((size_t)bh * T_ + m0) * S_;
    const _Float16* vbase = vhT + (size_t)bh * D_ * S_;
    char* AsB = (char*)As;
    char* BsB = (char*)Bs;

    const int brow = w * 8 + (l >> 3);           // B staged row (d)
    const int bsg  = (l & 7) ^ (brow & 7);       // swizzled source chunk

    f4 acc[4];
#pragma unroll
    for (int mi = 0; mi < 4; ++mi) acc[mi] = (f4){0.f, 0.f, 0.f, 0.f};

    for (int k0 = 0; k0 < 1024; k0 += 64) {
        // B: 8KB via one DMA per wave
        gload_lds16(&vbase[(size_t)brow * S_ + k0 + bsg * 8], BsB + w * 1024);
        // A: 128 rows x 8 chunks; thread handles slots tid and tid+512
#pragma unroll
        for (int i = 0; i < 2; ++i) {
            int slot = tid + i * 512;
            int row = slot >> 3, ch = slot & 7;
            const float* src = &abase[(size_t)row * S_ + k0 + ch * 8];
            float4 x0 = *(const float4*)src;
            float4 x1 = *(const float4*)(src + 4);
            h8 va;
            va[0] = (_Float16)x0.x; va[1] = (_Float16)x0.y;
            va[2] = (_Float16)x0.z; va[3] = (_Float16)x0.w;
            va[4] = (_Float16)x1.x; va[5] = (_Float16)x1.y;
            va[6] = (_Float16)x1.z; va[7] = (_Float16)x1.w;
            *(h8*)(AsB + row * 128 + ((ch ^ (row & 7)) << 4)) = va;
        }
        __syncthreads();
#pragma unroll
        for (int kk = 0; kk < 2; ++kk) {
            h8 bf;
            {
                int r = wc * 16 + lr, kc = kk * 4 + lg;
                bf = *(const h8*)(BsB + r * 128 + ((kc ^ (r & 7)) << 4));
            }
#pragma unroll
            for (int mi = 0; mi < 4; ++mi) {
                int r = wr * 64 + mi * 16 + lr, kc = kk * 4 + lg;
                h8 af = *(const h8*)(AsB + r * 128 + ((kc ^ (r & 7)) << 4));
                acc[mi] = mfma16(af, bf, acc[mi]);
            }
        }
        __syncthreads();
    }

#pragma unroll
    for (int mi = 0; mi < 4; ++mi)
#pragma unroll
        for (int r = 0; r < 4; ++r) {
            int t = m0 + wr * 64 + mi * 16 + lg * 4 + r;
            int d = wc * 16 + lr;
            oh[((size_t)t * B_ + b) * E_ + h * 64 + d] = (_Float16)acc[mi][r];
        }
}

// ---------------------------------------------------------------------------
extern "C" void kernel_launch(void* const* d_in, const int* in_sizes, int n_in,
                              void* d_out, int out_size, void* d_ws, size_t ws_size,
                              hipStream_t stream)
{
    const float* q    = (const float*)d_in[0];
    const float* k    = (const float*)d_in[1];
    const float* v    = (const float*)d_in[2];
    const float* Wq   = (const float*)d_in[3];
    const float* Wk   = (const float*)d_in[4];
    const float* Wv   = (const float*)d_in[5];
    const float* Wp   = (const float*)d_in[6];
    const float* bp   = (const float*)d_in[7];
    const float* bias = (const float*)d_in[8];
    const int*   mask = (const int*)d_in[9];

    float* out  = (float*)d_out;               // (T,B,E) f32
    float* attn = out + (size_t)T_ * B_ * E_;  // (B,H,T,S) f32

    _Float16* qh   = (_Float16*)d_ws;          // (B,H,T,D)
    _Float16* kh   = qh + NH_;                 // (B,H,S,D)
    _Float16* vhT  = kh + NH_;                 // (B,H,D,S)
    _Float16* oh   = vhT + NH_;                // (T,B,E)
    _Float16* q16  = oh + NH_;                 // contiguous cvt_all dst
    _Float16* k16  = q16 + NH_;
    _Float16* v16  = k16 + NH_;
    _Float16* Wq16 = v16 + NH_;
    _Float16* Wk16 = Wq16 + EE_;
    _Float16* Wv16 = Wk16 + EE_;
    _Float16* Wp16 = Wv16 + EE_;

    dim3 blk(512);

    cvt_all<<<dim3(8192), dim3(256), 0, stream>>>(q, k, v, Wq, Wk, Wv, Wp, q16);

    qkv_gemm<<<dim3(64, 8, 3), blk, 0, stream>>>(
        q16, k16, v16, Wq16, Wk16, Wv16, qh, kh, vhT);

    score_attn<<<dim3(4096), blk, 0, stream>>>(qh, kh, bias, mask, attn);

    pv_heads<<<dim3(8, 64), blk, 0, stream>>>(attn, vhT, oh);

    out_gemm<<<dim3(64, 8), blk, 0, stream>>>(oh, Wp16, bp, out);
}